// Round 7
// baseline (135.945 us; speedup 1.0000x reference)
//
#include <hip/hip_runtime.h>

#define NXg 4096
#define NYg 4096
#define ROW0 8                 // row kernel covers rows [8, 4087]
#define NROWS 4080

static constexpr float C = 10.2375f;   // Z*DT/DX = (1/400)*4095 ; DX==DY

struct F4  { float v[4];  };   // cols c0   .. c0+3
struct F7  { float v[7];  };   // cols c0-1 .. c0+5
struct F10 { float v[10]; };   // cols c0-3 .. c0+6

// Load 12 consecutive floats at row r, cols c0-4 .. c0+7 (three aligned float4).
// In-bounds for rows in [5, 4090]. At col edges the outer float4s contain
// neighboring-row data; consumed only by lanes whose results are overridden
// by gL/gR fixups.
__device__ __forceinline__ void ld12(const float* __restrict__ P, int r, int c0,
                                     float4& a, float4& b, float4& c) {
    const size_t o = (size_t)r * NYg + c0;
    a = *(const float4*)(P + o - 4);
    b = *(const float4*)(P + o);
    c = *(const float4*)(P + o + 4);
}
__device__ __forceinline__ F7 ld7(const float* __restrict__ P, int r, int c0) {
    float4 a, b, c; ld12(P, r, c0, a, b, c);
    F7 x;
    x.v[0] = a.w; x.v[1] = b.x; x.v[2] = b.y; x.v[3] = b.z;
    x.v[4] = b.w; x.v[5] = c.x; x.v[6] = c.y;
    return x;
}
__device__ __forceinline__ F10 ld10(const float* __restrict__ P, int r, int c0) {
    float4 a, b, c; ld12(P, r, c0, a, b, c);
    F10 x;
    x.v[0] = a.y; x.v[1] = a.z; x.v[2] = a.w;
    x.v[3] = b.x; x.v[4] = b.y; x.v[5] = b.z; x.v[6] = b.w;
    x.v[7] = c.x; x.v[8] = c.y; x.v[9] = c.z;
    return x;
}
__device__ __forceinline__ F4 ldb(const float* __restrict__ P, int r, int c0) {
    const float4 b = *(const float4*)(P + (size_t)r * NYg + c0);
    F4 x; x.v[0] = b.x; x.v[1] = b.y; x.v[2] = b.z; x.v[3] = b.w;
    return x;
}
__device__ __forceinline__ F4 mid(const F7& s) {   // cols c0..c0+3 of a F7
    F4 x; x.v[0] = s.v[1]; x.v[1] = s.v[2]; x.v[2] = s.v[3]; x.v[3] = s.v[4];
    return x;
}

// ---------------------------------------------------------------------------
// Row kernel: one thread = one output row x 4 cols. All 33 loads are
// independent straight-line code (no loop-carried deps -> scheduler batches
// them; rounds 4-6 showed rolling-window loops serialize to ~1-2 MLP).
// E[i] computed 7-wide; E[i-1], E[i+1], E[i+2] computed 4-wide.
// ---------------------------------------------------------------------------
__global__ __launch_bounds__(256) void row_kernel(
    const float* __restrict__ X1, const float* __restrict__ X2,
    const float* __restrict__ X3, const float* __restrict__ w1,
    float* __restrict__ E, float* __restrict__ Hx, float* __restrict__ Hy)
{
    const int t  = threadIdx.x;
    const int c0 = (blockIdx.x * 256 + t) * 4;
    const int i  = ROW0 + blockIdx.y;        // output row, in [8, 4087]
    const bool gL = (c0 == 0);
    const bool gR = (c0 == NYg - 4);

    const float wv = w1[0];
    const float f0 = (wv - 1.0f) / 3.0f;
    const float f1 = -wv;
    const float f2 = wv;
    const float f3 = (1.0f - wv) / 3.0f;

    // ---------------- loads (rows i-3 .. i+3, all in [5, 4090]) ----------------
    const F4  x3m3 = ldb(X3, i - 3, c0);
    const F7  x3m2 = ld7(X3, i - 2, c0);
    const F7  x3m1 = ld7(X3, i - 1, c0);
    const F7  x3i  = ld7(X3, i,     c0);
    const F7  x3p1 = ld7(X3, i + 1, c0);
    const F4  x3p2 = ldb(X3, i + 2, c0);
    const F4  x3p3 = ldb(X3, i + 3, c0);

    const F10 x2m1 = ld10(X2, i - 1, c0);
    const F10 x2i  = ld10(X2, i,     c0);
    const F10 x2p1 = ld10(X2, i + 1, c0);
    const F10 x2p2 = ld10(X2, i + 2, c0);

    const F4  x1m1 = ldb(X1, i - 1, c0);
    const F7  x1i  = ld7(X1, i,     c0);
    const F4  x1p1 = ldb(X1, i + 1, c0);
    const F4  x1p2 = ldb(X1, i + 2, c0);

    // ---------------- E row i, 7-wide (cols c0-1 .. c0+5) ----------------
    F7 e7;
    #pragma unroll
    for (int m = 0; m < 7; ++m) {
        const float e1 = x1i.v[m] + C * (x3i.v[m] - x3m1.v[m])
                                  - C * (x2i.v[m + 2] - x2i.v[m + 1]);
        e7.v[m] = e1
            + C * (f0 * x3m2.v[m] + f1 * x3m1.v[m] + f2 * x3i.v[m] + f3 * x3p1.v[m])
            - C * (f0 * x2i.v[m] + f1 * x2i.v[m + 1] + f2 * x2i.v[m + 2] + f3 * x2i.v[m + 3]);
    }
    if (gL) {
        e7.v[1] = x1i.v[1];                                     // j=0: copy
        e7.v[2] = x1i.v[2] + C * (x3i.v[2] - x3m1.v[2])
                           - C * (x2i.v[4] - x2i.v[3]);         // j=1: BC only
    }
    if (gR) {
        e7.v[4] = x1i.v[4];                                     // j=4095: copy
        e7.v[3] = x1i.v[3] + C * (x3i.v[3] - x3m1.v[3])
                           - C * (x2i.v[5] - x2i.v[4]);         // j=4094: BC only
    }

    // ---------------- E rows i-1, i+1, i+2, 4-wide (cols c0..c0+3) ----------------
    auto eRow4 = [&](const F4& a, const F4& b, const F4& cc, const F4& d,
                     const F10& x2r, const F4& x1r) -> F4 {
        F4 e;
        #pragma unroll
        for (int q = 0; q < 4; ++q) {
            const float e1 = x1r.v[q] + C * (cc.v[q] - b.v[q])
                                      - C * (x2r.v[q + 3] - x2r.v[q + 2]);
            e.v[q] = e1
                + C * (f0 * a.v[q] + f1 * b.v[q] + f2 * cc.v[q] + f3 * d.v[q])
                - C * (f0 * x2r.v[q + 1] + f1 * x2r.v[q + 2]
                     + f2 * x2r.v[q + 3] + f3 * x2r.v[q + 4]);
        }
        if (gL) {
            e.v[0] = x1r.v[0];                                  // j=0: copy
            e.v[1] = x1r.v[1] + C * (cc.v[1] - b.v[1])
                              - C * (x2r.v[4] - x2r.v[3]);      // j=1: BC only
        }
        if (gR) {
            e.v[3] = x1r.v[3];                                  // j=4095: copy
            e.v[2] = x1r.v[2] + C * (cc.v[2] - b.v[2])
                              - C * (x2r.v[5] - x2r.v[4]);      // j=4094: BC only
        }
        return e;
    };

    const F4 em1 = eRow4(x3m3,      mid(x3m2), mid(x3m1), mid(x3i), x2m1, x1m1);
    const F4 ep1 = eRow4(mid(x3m1), mid(x3i),  mid(x3p1), x3p2,     x2p1, x1p1);
    const F4 ep2 = eRow4(mid(x3i),  mid(x3p1), x3p2,      x3p3,     x2p2, x1p2);

    // ---------------- outputs ----------------
    float hx[4], hy[4];
    #pragma unroll
    for (int q = 0; q < 4; ++q) {
        hx[q] = x2i.v[q + 3] - C * (x1i.v[q + 2] - x1i.v[q + 1])
              - C * (f0 * e7.v[q] + f1 * e7.v[q + 1]
                   + f2 * e7.v[q + 2] + f3 * e7.v[q + 3]);
        hy[q] = x3i.v[q + 1] + C * (x1p1.v[q] - x1i.v[q + 1])
              + C * (f0 * em1.v[q] + f1 * e7.v[q + 1]
                   + f2 * ep1.v[q] + f3 * ep2.v[q]);
    }
    if (gL) {
        hx[0] = x2i.v[3] - C * (x1i.v[2] - x1i.v[1]);           // j=0: no f4
        hy[0] = x3i.v[1];                                       // j=0: copy X3
        hy[1] = x3i.v[2] + C * (x1p1.v[1] - x1i.v[2]);          // j=1: no f4
    }
    if (gR) {
        hx[3] = x2i.v[6];                                       // j=4095: copy X2
        hy[3] = x3i.v[4];                                       // j=4095: copy X3
        hx[2] = x2i.v[5] - C * (x1i.v[4] - x1i.v[3]);           // j=4094: no f4
        hy[2] = x3i.v[3] + C * (x1p1.v[2] - x1i.v[3]);          // j=4094: no f4
    }

    const size_t idx = (size_t)i * NYg + c0;
    *(float4*)(E  + idx) = make_float4(e7.v[1], e7.v[2], e7.v[3], e7.v[4]);
    *(float4*)(Hx + idx) = make_float4(hx[0], hx[1], hx[2], hx[3]);
    *(float4*)(Hy + idx) = make_float4(hy[0], hy[1], hy[2], hy[3]);
}

// ---------------------------------------------------------------------------
// Edge kernel: boundary row bands [0,7] and [4088,4095], fully guarded.
// ---------------------------------------------------------------------------
#define TRE 8
#define EROWSE 12
#define ECOLSE 136

__global__ __launch_bounds__(256) void edge_kernel(
    const float* __restrict__ X1, const float* __restrict__ X2,
    const float* __restrict__ X3, const float* __restrict__ w1,
    float* __restrict__ E, float* __restrict__ Hx, float* __restrict__ Hy)
{
    __shared__ float elds[EROWSE][ECOLSE];
    const int t    = threadIdx.x;
    const int row0 = blockIdx.y ? (NXg - TRE) : 0;
    const int col0 = blockIdx.x * 128;

    const float wv = w1[0];
    const float f0 = (wv - 1.0f) / 3.0f;
    const float f1 = -wv;
    const float f2 = wv;
    const float f3 = (1.0f - wv) / 3.0f;

    for (int cidx = t; cidx < EROWSE * ECOLSE; cidx += 256) {
        const int r  = cidx / ECOLSE;
        const int cc = cidx - r * ECOLSE;
        const int gr = row0 - 2 + r;
        const int gc = col0 - 4 + cc;
        float e = 0.0f;
        if (gr >= 0 && gr < NXg && gc >= 0 && gc < NYg) {
            const size_t idx = (size_t)gr * NYg + gc;
            const float x1 = X1[idx];
            if (gr == 0 || gr == NXg - 1 || gc == 0 || gc == NYg - 1) {
                e = x1;
            } else {
                float e1 = x1 + C * (X3[idx] - X3[idx - NYg])
                              - C * (X2[idx] - X2[idx - 1]);
                if (gr >= 2 && gr <= NXg - 3 && gc >= 2 && gc <= NYg - 3) {
                    e1 += C * (f0 * X3[idx - 2 * NYg] + f1 * X3[idx - NYg]
                             + f2 * X3[idx] + f3 * X3[idx + NYg])
                        - C * (f0 * X2[idx - 2] + f1 * X2[idx - 1]
                             + f2 * X2[idx] + f3 * X2[idx + 1]);
                }
                e = e1;
            }
        }
        elds[r][cc] = e;
    }
    __syncthreads();

    for (int cidx = t; cidx < TRE * 128; cidx += 256) {
        const int hr  = cidx >> 7;
        const int tc  = cidx & 127;
        const int gr  = row0 + hr;
        const int gcc = col0 + tc;
        const size_t idx = (size_t)gr * NYg + gcc;
        const int lr  = hr + 2;
        const int lc2 = tc + 4;

        const float ec = elds[lr][lc2];
        E[idx] = ec;

        const float x1 = X1[idx];

        float hx = X2[idx];
        if (gr >= 1 && gr <= NXg - 2 && gcc <= NYg - 2)
            hx -= C * (X1[idx + 1] - x1);
        if (gr >= 2 && gr <= NXg - 3 && gcc >= 1 && gcc <= NYg - 3) {
            hx -= C * (f0 * elds[lr][lc2 - 1] + f1 * ec
                     + f2 * elds[lr][lc2 + 1] + f3 * elds[lr][lc2 + 2]);
        }
        Hx[idx] = hx;

        float hy = X3[idx];
        if (gr <= NXg - 2 && gcc >= 1 && gcc <= NYg - 2)
            hy += C * (X1[idx + NYg] - x1);
        if (gr >= 1 && gr <= NXg - 3 && gcc >= 2 && gcc <= NYg - 3) {
            hy += C * (f0 * elds[lr - 1][lc2] + f1 * ec
                     + f2 * elds[lr + 1][lc2] + f3 * elds[lr + 2][lc2]);
        }
        Hy[idx] = hy;
    }
}

extern "C" void kernel_launch(void* const* d_in, const int* in_sizes, int n_in,
                              void* d_out, int out_size, void* d_ws, size_t ws_size,
                              hipStream_t stream) {
    const float* X1 = (const float*)d_in[0];
    const float* X2 = (const float*)d_in[1];
    const float* X3 = (const float*)d_in[2];
    const float* w1 = (const float*)d_in[3];

    float* E  = (float*)d_out;
    float* Hx = (float*)d_out + (size_t)NXg * NYg;
    float* Hy = (float*)d_out + 2 * (size_t)NXg * NYg;

    // row kernel first (bulk), edge kernel second (fills the tail)
    row_kernel <<<dim3(NYg / 1024, NROWS), 256, 0, stream>>>(X1, X2, X3, w1, E, Hx, Hy);
    edge_kernel<<<dim3(32, 2), 256, 0, stream>>>(X1, X2, X3, w1, E, Hx, Hy);
}

// Round 8
// 99.653 us; speedup vs baseline: 1.3642x; 1.3642x over previous
//
#include <hip/hip_runtime.h>

#define NXg 4096
#define NYg 4096
#define RPT 8                  // output rows per thread (fat kernel)
#define ROW0 8                 // fat kernel covers rows [8, 4087]
#define NBANDS 510             // (4088-8)/RPT
#define BTHREADS 128           // threads per block (2 waves); block covers 512 cols

static constexpr float C = 10.2375f;   // Z*DT/DX = (1/400)*4095 ; DX==DY

struct F7  { float v[7];  };   // cols c0-1 .. c0+5
struct F10 { float v[10]; };   // cols c0-3 .. c0+6

// Load 12 consecutive floats at row r, cols c0-4 .. c0+7 (three aligned float4).
// In-bounds for all uses: r in [5, 4091]. At col edges the outer float4s contain
// neighboring-row data; consumed only by lanes whose results are overridden by
// gL/gR fixups.
__device__ __forceinline__ void ld12(const float* __restrict__ P, int r, int c0,
                                     float4& a, float4& b, float4& c) {
    const size_t o = (size_t)r * NYg + c0;
    a = *(const float4*)(P + o - 4);
    b = *(const float4*)(P + o);
    c = *(const float4*)(P + o + 4);
}

__device__ __forceinline__ F7 mk7(const float4& a, const float4& b, const float4& c) {
    F7 r;
    r.v[0] = a.w; r.v[1] = b.x; r.v[2] = b.y; r.v[3] = b.z;
    r.v[4] = b.w; r.v[5] = c.x; r.v[6] = c.y;
    return r;
}
__device__ __forceinline__ F10 mk10(const float4& a, const float4& b, const float4& c) {
    F10 r;
    r.v[0] = a.y; r.v[1] = a.z; r.v[2] = a.w;
    r.v[3] = b.x; r.v[4] = b.y; r.v[5] = b.z; r.v[6] = b.w;
    r.v[7] = c.x; r.v[8] = c.y; r.v[9] = c.z;
    return r;
}

__device__ __forceinline__ F7 ld7(const float* __restrict__ P, int r, int c0) {
    float4 a, b, c; ld12(P, r, c0, a, b, c); return mk7(a, b, c);
}
__device__ __forceinline__ F10 ld10(const float* __restrict__ P, int r, int c0) {
    float4 a, b, c; ld12(P, r, c0, a, b, c); return mk10(a, b, c);
}

// ---------------------------------------------------------------------------
// Fat kernel: rows [8, 4087]. Thread owns cols c0..c0+3, walks RPT rows with
// rolling register windows; E computed 7-wide so no cross-thread exchange.
//
// KEY FIX (r7 evidence): LLVM's pre-RA scheduler sinks every load to its
// first use to minimize VGPR pressure (VGPR stuck at 64 across r4-r7,
// MLP ~1-2, both pipes idle). __builtin_amdgcn_sched_barrier(0) after each
// prefetch group pins the loads BEFORE the barrier and all consumers after,
// forcing the 9 next-row loads to stay in flight across the current row's
// compute. launch_bounds(128,2) gives the 256-VGPR budget this needs.
// ---------------------------------------------------------------------------
__global__ __launch_bounds__(BTHREADS, 2) void fat_kernel(
    const float* __restrict__ X1, const float* __restrict__ X2,
    const float* __restrict__ X3, const float* __restrict__ w1,
    float* __restrict__ E, float* __restrict__ Hx, float* __restrict__ Hy)
{
    const int t  = threadIdx.x;
    const int c0 = (blockIdx.x * BTHREADS + t) * 4;
    const int i0 = ROW0 + blockIdx.y * RPT;
    const bool gL = (c0 == 0);
    const bool gR = (c0 == NYg - 4);

    const float wv = w1[0];
    const float f0 = (wv - 1.0f) / 3.0f;
    const float f1 = -wv;
    const float f2 = wv;
    const float f3 = (1.0f - wv) / 3.0f;

    auto eRow = [&](const F7& x3m2, const F7& x3m1, const F7& x3p0, const F7& x3p1,
                    const F10& x2r, const F7& x1r) -> F7 {
        F7 e;
        #pragma unroll
        for (int m = 0; m < 7; ++m) {
            const float e1 = x1r.v[m] + C * (x3p0.v[m] - x3m1.v[m])
                                      - C * (x2r.v[m + 2] - x2r.v[m + 1]);
            e.v[m] = e1
                + C * (f0 * x3m2.v[m] + f1 * x3m1.v[m] + f2 * x3p0.v[m] + f3 * x3p1.v[m])
                - C * (f0 * x2r.v[m] + f1 * x2r.v[m + 1] + f2 * x2r.v[m + 2] + f3 * x2r.v[m + 3]);
        }
        if (gL) {
            e.v[1] = x1r.v[1];                                  // j=0: copy
            e.v[2] = x1r.v[2] + C * (x3p0.v[2] - x3m1.v[2])
                              - C * (x2r.v[4] - x2r.v[3]);      // j=1: BC only
        }
        if (gR) {
            e.v[4] = x1r.v[4];                                  // j=4095: copy
            e.v[3] = x1r.v[3] + C * (x3p0.v[3] - x3m1.v[3])
                              - C * (x2r.v[5] - x2r.v[4]);      // j=4094: BC only
        }
        return e;
    };

    // ---------------- Prologue: fill windows for i = i0 ----------------
    F7 p3a = ld7(X3, i0 - 3, c0);
    F7 p3b = ld7(X3, i0 - 2, c0);
    F7 p3c = ld7(X3, i0 - 1, c0);
    F7 w3[4];
    w3[0] = ld7(X3, i0,     c0);
    w3[1] = ld7(X3, i0 + 1, c0);
    w3[2] = ld7(X3, i0 + 2, c0);
    w3[3] = ld7(X3, i0 + 3, c0);

    F10 q2a = ld10(X2, i0 - 1, c0);
    F10 q2b = ld10(X2, i0,     c0);
    F10 q2c = ld10(X2, i0 + 1, c0);
    F10 w2r = ld10(X2, i0 + 2, c0);   // X2 row i+2

    F7 q1a = ld7(X1, i0 - 1, c0);
    F7 w1r[3];
    w1r[0] = ld7(X1, i0,     c0);
    w1r[1] = ld7(X1, i0 + 1, c0);
    w1r[2] = ld7(X1, i0 + 2, c0);

    // pin: all 48 prologue loads issued before any compute
    __builtin_amdgcn_sched_barrier(0);

    F7 ew[4];                          // E rows i-1 .. i+2
    ew[0] = eRow(p3a, p3b, p3c, w3[0], q2a, q1a);        // E[i0-1]
    ew[1] = eRow(p3b, p3c, w3[0], w3[1], q2b, w1r[0]);   // E[i0]
    ew[2] = eRow(p3c, w3[0], w3[1], w3[2], q2c, w1r[1]); // E[i0+1]

    float x2c0[4] = {q2b.v[3], q2b.v[4], q2b.v[5], q2b.v[6]};  // X2[i] centers
    float x2c1[4] = {q2c.v[3], q2c.v[4], q2c.v[5], q2c.v[6]};  // X2[i+1] centers

    // ---------------- Main loop over output rows ----------------
    #pragma unroll
    for (int s = 0; s < RPT; ++s) {
        const int i = i0 + s;

        // issue next-step loads early (consumed next iteration)
        F7  t3; F10 t2; F7 t1;
        if (s < RPT - 1) {
            t3 = ld7(X3, i + 4, c0);
            t2 = ld10(X2, i + 3, c0);
            t1 = ld7(X1, i + 3, c0);
        }
        // pin: the 9 prefetch loads stay in flight across this row's compute
        __builtin_amdgcn_sched_barrier(0);

        // E row i+2 from already-resident windows
        ew[3] = eRow(w3[0], w3[1], w3[2], w3[3], w2r, w1r[2]);

        // ---- outputs for row i ----
        float hx[4], hy[4];
        #pragma unroll
        for (int q = 0; q < 4; ++q) {
            hx[q] = x2c0[q] - C * (w1r[0].v[q + 2] - w1r[0].v[q + 1])
                  - C * (f0 * ew[1].v[q]     + f1 * ew[1].v[q + 1]
                       + f2 * ew[1].v[q + 2] + f3 * ew[1].v[q + 3]);
            hy[q] = w3[0].v[q + 1] + C * (w1r[1].v[q + 1] - w1r[0].v[q + 1])
                  + C * (f0 * ew[0].v[q + 1] + f1 * ew[1].v[q + 1]
                       + f2 * ew[2].v[q + 1] + f3 * ew[3].v[q + 1]);
        }
        if (gL) {
            hx[0] = x2c0[0] - C * (w1r[0].v[2] - w1r[0].v[1]);    // j=0: no f4
            hy[0] = w3[0].v[1];                                   // j=0: copy X3
            hy[1] = w3[0].v[2] + C * (w1r[1].v[2] - w1r[0].v[2]); // j=1: no f4
        }
        if (gR) {
            hx[3] = x2c0[3];                                      // j=4095: copy X2
            hy[3] = w3[0].v[4];                                   // j=4095: copy X3
            hx[2] = x2c0[2] - C * (w1r[0].v[4] - w1r[0].v[3]);    // j=4094: no f4
            hy[2] = w3[0].v[3] + C * (w1r[1].v[3] - w1r[0].v[3]); // j=4094: no f4
        }

        const size_t idx = (size_t)i * NYg + c0;
        *(float4*)(E  + idx) = make_float4(ew[1].v[1], ew[1].v[2], ew[1].v[3], ew[1].v[4]);
        *(float4*)(Hx + idx) = make_float4(hx[0], hx[1], hx[2], hx[3]);
        *(float4*)(Hy + idx) = make_float4(hy[0], hy[1], hy[2], hy[3]);

        // ---- roll windows ----
        ew[0] = ew[1]; ew[1] = ew[2]; ew[2] = ew[3];
        w3[0] = w3[1]; w3[1] = w3[2]; w3[2] = w3[3];
        w1r[0] = w1r[1]; w1r[1] = w1r[2];
        #pragma unroll
        for (int q = 0; q < 4; ++q) { x2c0[q] = x2c1[q]; x2c1[q] = w2r.v[3 + q]; }
        if (s < RPT - 1) { w3[3] = t3; w2r = t2; w1r[2] = t1; }
    }
}

// ---------------------------------------------------------------------------
// Edge kernel: boundary row bands [0,7] and [4088,4095], fully guarded.
// ---------------------------------------------------------------------------
#define TRE 8
#define EROWSE 12
#define ECOLSE 136

__global__ __launch_bounds__(256) void edge_kernel(
    const float* __restrict__ X1, const float* __restrict__ X2,
    const float* __restrict__ X3, const float* __restrict__ w1,
    float* __restrict__ E, float* __restrict__ Hx, float* __restrict__ Hy)
{
    __shared__ float elds[EROWSE][ECOLSE];
    const int t    = threadIdx.x;
    const int row0 = blockIdx.y ? (NXg - TRE) : 0;
    const int col0 = blockIdx.x * 128;

    const float wv = w1[0];
    const float f0 = (wv - 1.0f) / 3.0f;
    const float f1 = -wv;
    const float f2 = wv;
    const float f3 = (1.0f - wv) / 3.0f;

    for (int cidx = t; cidx < EROWSE * ECOLSE; cidx += 256) {
        const int r  = cidx / ECOLSE;
        const int cc = cidx - r * ECOLSE;
        const int gr = row0 - 2 + r;
        const int gc = col0 - 4 + cc;
        float e = 0.0f;
        if (gr >= 0 && gr < NXg && gc >= 0 && gc < NYg) {
            const size_t idx = (size_t)gr * NYg + gc;
            const float x1 = X1[idx];
            if (gr == 0 || gr == NXg - 1 || gc == 0 || gc == NYg - 1) {
                e = x1;
            } else {
                float e1 = x1 + C * (X3[idx] - X3[idx - NYg])
                              - C * (X2[idx] - X2[idx - 1]);
                if (gr >= 2 && gr <= NXg - 3 && gc >= 2 && gc <= NYg - 3) {
                    e1 += C * (f0 * X3[idx - 2 * NYg] + f1 * X3[idx - NYg]
                             + f2 * X3[idx] + f3 * X3[idx + NYg])
                        - C * (f0 * X2[idx - 2] + f1 * X2[idx - 1]
                             + f2 * X2[idx] + f3 * X2[idx + 1]);
                }
                e = e1;
            }
        }
        elds[r][cc] = e;
    }
    __syncthreads();

    for (int cidx = t; cidx < TRE * 128; cidx += 256) {
        const int hr  = cidx >> 7;
        const int tc  = cidx & 127;
        const int gr  = row0 + hr;
        const int gcc = col0 + tc;
        const size_t idx = (size_t)gr * NYg + gcc;
        const int lr  = hr + 2;
        const int lc2 = tc + 4;

        const float ec = elds[lr][lc2];
        E[idx] = ec;

        const float x1 = X1[idx];

        float hx = X2[idx];
        if (gr >= 1 && gr <= NXg - 2 && gcc <= NYg - 2)
            hx -= C * (X1[idx + 1] - x1);
        if (gr >= 2 && gr <= NXg - 3 && gcc >= 1 && gcc <= NYg - 3) {
            hx -= C * (f0 * elds[lr][lc2 - 1] + f1 * ec
                     + f2 * elds[lr][lc2 + 1] + f3 * elds[lr][lc2 + 2]);
        }
        Hx[idx] = hx;

        float hy = X3[idx];
        if (gr <= NXg - 2 && gcc >= 1 && gcc <= NYg - 2)
            hy += C * (X1[idx + NYg] - x1);
        if (gr >= 1 && gr <= NXg - 3 && gcc >= 2 && gcc <= NYg - 3) {
            hy += C * (f0 * elds[lr - 1][lc2] + f1 * ec
                     + f2 * elds[lr + 1][lc2] + f3 * elds[lr + 2][lc2]);
        }
        Hy[idx] = hy;
    }
}

extern "C" void kernel_launch(void* const* d_in, const int* in_sizes, int n_in,
                              void* d_out, int out_size, void* d_ws, size_t ws_size,
                              hipStream_t stream) {
    const float* X1 = (const float*)d_in[0];
    const float* X2 = (const float*)d_in[1];
    const float* X3 = (const float*)d_in[2];
    const float* w1 = (const float*)d_in[3];

    float* E  = (float*)d_out;
    float* Hx = (float*)d_out + (size_t)NXg * NYg;
    float* Hy = (float*)d_out + 2 * (size_t)NXg * NYg;

    edge_kernel<<<dim3(32, 2), 256, 0, stream>>>(X1, X2, X3, w1, E, Hx, Hy);
    fat_kernel <<<dim3(NYg / (BTHREADS * 4), NBANDS), BTHREADS, 0, stream>>>(
        X1, X2, X3, w1, E, Hx, Hy);
}

// Round 9
// 98.035 us; speedup vs baseline: 1.3867x; 1.0165x over previous
//
#include <hip/hip_runtime.h>

#define NXg 4096
#define NYg 4096
#define BROWS 8                // core rows per block
#define ROW0 8                 // band region covers rows [8, 4088)
#define NBANDS 510             // 4080 / BROWS
#define NPANEL 16              // 4096 / CCOLS
#define CCOLS 256              // core cols per block
#define LCOLS 264              // LDS cols: core + 4 halo each side
#define R3 14                  // X3 LDS rows: global i0-3 .. i0+10
#define R2 11                  // X2 LDS rows: global i0-1 .. i0+9
#define R1 11                  // X1 LDS rows: global i0-1 .. i0+9

static constexpr float C = 10.2375f;   // Z*DT/DX = (1/400)*4095 ; DX==DY

struct F7  { float v[7];  };
struct F10 { float v[10]; };

__device__ __forceinline__ F7 mk7(const float4& a, const float4& b, const float4& c) {
    F7 r;
    r.v[0] = a.w; r.v[1] = b.x; r.v[2] = b.y; r.v[3] = b.z;
    r.v[4] = b.w; r.v[5] = c.x; r.v[6] = c.y;
    return r;
}
__device__ __forceinline__ F10 mk10(const float4& a, const float4& b, const float4& c) {
    F10 r;
    r.v[0] = a.y; r.v[1] = a.z; r.v[2] = a.w;
    r.v[3] = b.x; r.v[4] = b.y; r.v[5] = b.z; r.v[6] = b.w;
    r.v[7] = c.x; r.v[8] = c.y; r.v[9] = c.z;
    return r;
}
// LDS window readers: window centered at local col lc (lc = 4 + 4*quad, 16B-aligned)
__device__ __forceinline__ F7 l7(const float* Lrow, int lc) {
    const float4 a = *(const float4*)(Lrow + lc - 4);
    const float4 b = *(const float4*)(Lrow + lc);
    const float4 c = *(const float4*)(Lrow + lc + 4);
    return mk7(a, b, c);
}
__device__ __forceinline__ F10 l10(const float* Lrow, int lc) {
    const float4 a = *(const float4*)(Lrow + lc - 4);
    const float4 b = *(const float4*)(Lrow + lc);
    const float4 c = *(const float4*)(Lrow + lc + 4);
    return mk10(a, b, c);
}

// async global->LDS, 16B per lane: LDS dest = uniform base + lane*16
__device__ __forceinline__ void gload_lds16(const float* g, float* l) {
    __builtin_amdgcn_global_load_lds(
        (const __attribute__((address_space(1))) void*)g,
        (__attribute__((address_space(3))) void*)l, 16, 0, 0);
}

// ---------------------------------------------------------------------------
// Band kernel: rows [8, 4088). Block = 8 rows x 256 cols, 128 threads.
// Phase 1: DMA-fill X1/X2/X3 ext tiles into LDS via global_load_lds (the DMA
//   queue holds ~38KB/block in flight -> MLP decoupled from VGPRs, which
//   rounds 4-8 proved is the binding constraint at ~3.1 TB/s).
// Phase 2: proven fat-kernel rolling-window math, windows read from LDS.
// ---------------------------------------------------------------------------
__global__ __launch_bounds__(128, 2) void band_kernel(
    const float* __restrict__ X1, const float* __restrict__ X2,
    const float* __restrict__ X3, const float* __restrict__ w1,
    float* __restrict__ E, float* __restrict__ Hx, float* __restrict__ Hy)
{
    __shared__ float L3[R3][LCOLS];
    __shared__ float L2[R2][LCOLS];
    __shared__ float L1[R1][LCOLS];

    const int i0   = ROW0 + blockIdx.y * BROWS;
    const int col0 = blockIdx.x * CCOLS;
    const int wid  = threadIdx.x >> 6;
    const int lane = threadIdx.x & 63;

    // ---------------- Phase 1: async fill (72 chunks, 2 waves) ----------------
    // Each chunk: one row, part 0 covers local cols [0,256), part 1 [8,264).
    // Overlap [8,256) is written twice with IDENTICAL bytes (same global data,
    // shifted mapping) -> benign. Col under/overflow at panel edges reads
    // neighboring-row data (always in-bounds for global rows in [5,4090]);
    // consumed only by lanes whose results the gL/gR fixups override.
    for (int q = wid; q < 2 * (R3 + R2 + R1); q += 2) {
        const int part = q & 1;
        const int rid  = q >> 1;
        const float* src;
        float* lrow;
        int grow;
        if (rid < R3)           { src = X3; lrow = &L3[rid][0];           grow = i0 - 3 + rid; }
        else if (rid < R3 + R2) { src = X2; lrow = &L2[rid - R3][0];      grow = i0 - 1 + (rid - R3); }
        else                    { src = X1; lrow = &L1[rid - R3 - R2][0]; grow = i0 - 1 + (rid - R3 - R2); }
        const float* g = src + (size_t)grow * NYg + (col0 - 4 + part * 8) + lane * 4;
        gload_lds16(g, lrow + part * 8);
    }
    __syncthreads();   // drains the DMA queue (vmcnt(0)) + barrier

    // ---------------- Phase 2: compute from LDS ----------------
    const int cq = threadIdx.x & 63;          // col quad 0..63
    const int g  = threadIdx.x >> 6;          // row group 0..1
    const int lc = 4 + 4 * cq;                // local col of quad start
    const int rb = 4 * g;                     // first output row offset in band
    const int b3 = rb + 3;                    // L3 row of global (i0+rb)
    const int b2 = rb + 1;                    // L2/L1 row of global (i0+rb)

    const bool gL = (blockIdx.x == 0) && (cq == 0);
    const bool gR = (blockIdx.x == NPANEL - 1) && (cq == 63);

    const float wv = w1[0];
    const float f0 = (wv - 1.0f) / 3.0f;
    const float f1 = -wv;
    const float f2 = wv;
    const float f3 = (1.0f - wv) / 3.0f;

    auto eRow = [&](const F7& x3m2, const F7& x3m1, const F7& x3p0, const F7& x3p1,
                    const F10& x2r, const F7& x1r) -> F7 {
        F7 e;
        #pragma unroll
        for (int m = 0; m < 7; ++m) {
            const float e1 = x1r.v[m] + C * (x3p0.v[m] - x3m1.v[m])
                                      - C * (x2r.v[m + 2] - x2r.v[m + 1]);
            e.v[m] = e1
                + C * (f0 * x3m2.v[m] + f1 * x3m1.v[m] + f2 * x3p0.v[m] + f3 * x3p1.v[m])
                - C * (f0 * x2r.v[m] + f1 * x2r.v[m + 1] + f2 * x2r.v[m + 2] + f3 * x2r.v[m + 3]);
        }
        if (gL) {
            e.v[1] = x1r.v[1];                                  // j=0: copy
            e.v[2] = x1r.v[2] + C * (x3p0.v[2] - x3m1.v[2])
                              - C * (x2r.v[4] - x2r.v[3]);      // j=1: BC only
        }
        if (gR) {
            e.v[4] = x1r.v[4];                                  // j=4095: copy
            e.v[3] = x1r.v[3] + C * (x3p0.v[3] - x3m1.v[3])
                              - C * (x2r.v[5] - x2r.v[4]);      // j=4094: BC only
        }
        return e;
    };

    // Prologue: windows for first output row Rb = i0 + rb
    F7 p3a = l7(&L3[b3 - 3][0], lc);
    F7 p3b = l7(&L3[b3 - 2][0], lc);
    F7 p3c = l7(&L3[b3 - 1][0], lc);
    F7 w3[4];
    w3[0] = l7(&L3[b3][0],     lc);
    w3[1] = l7(&L3[b3 + 1][0], lc);
    w3[2] = l7(&L3[b3 + 2][0], lc);
    w3[3] = l7(&L3[b3 + 3][0], lc);

    F10 q2a = l10(&L2[b2 - 1][0], lc);
    F10 q2b = l10(&L2[b2][0],     lc);
    F10 q2c = l10(&L2[b2 + 1][0], lc);
    F10 w2r = l10(&L2[b2 + 2][0], lc);

    F7 q1a = l7(&L1[b2 - 1][0], lc);
    F7 w1r[3];
    w1r[0] = l7(&L1[b2][0],     lc);
    w1r[1] = l7(&L1[b2 + 1][0], lc);
    w1r[2] = l7(&L1[b2 + 2][0], lc);

    F7 ew[4];                      // E rows Rb-1 .. Rb+2
    ew[0] = eRow(p3a, p3b, p3c, w3[0], q2a, q1a);
    ew[1] = eRow(p3b, p3c, w3[0], w3[1], q2b, w1r[0]);
    ew[2] = eRow(p3c, w3[0], w3[1], w3[2], q2c, w1r[1]);

    float x2c0[4] = {q2b.v[3], q2b.v[4], q2b.v[5], q2b.v[6]};
    float x2c1[4] = {q2c.v[3], q2c.v[4], q2c.v[5], q2c.v[6]};

    #pragma unroll
    for (int s = 0; s < 4; ++s) {
        const int i = i0 + rb + s;

        // E row i+2 from resident windows
        ew[3] = eRow(w3[0], w3[1], w3[2], w3[3], w2r, w1r[2]);

        float hx[4], hy[4];
        #pragma unroll
        for (int q = 0; q < 4; ++q) {
            hx[q] = x2c0[q] - C * (w1r[0].v[q + 2] - w1r[0].v[q + 1])
                  - C * (f0 * ew[1].v[q]     + f1 * ew[1].v[q + 1]
                       + f2 * ew[1].v[q + 2] + f3 * ew[1].v[q + 3]);
            hy[q] = w3[0].v[q + 1] + C * (w1r[1].v[q + 1] - w1r[0].v[q + 1])
                  + C * (f0 * ew[0].v[q + 1] + f1 * ew[1].v[q + 1]
                       + f2 * ew[2].v[q + 1] + f3 * ew[3].v[q + 1]);
        }
        if (gL) {
            hx[0] = x2c0[0] - C * (w1r[0].v[2] - w1r[0].v[1]);    // j=0: no f4
            hy[0] = w3[0].v[1];                                   // j=0: copy X3
            hy[1] = w3[0].v[2] + C * (w1r[1].v[2] - w1r[0].v[2]); // j=1: no f4
        }
        if (gR) {
            hx[3] = x2c0[3];                                      // j=4095: copy X2
            hy[3] = w3[0].v[4];                                   // j=4095: copy X3
            hx[2] = x2c0[2] - C * (w1r[0].v[4] - w1r[0].v[3]);    // j=4094: no f4
            hy[2] = w3[0].v[3] + C * (w1r[1].v[3] - w1r[0].v[3]); // j=4094: no f4
        }

        const size_t idx = (size_t)i * NYg + col0 + 4 * cq;
        *(float4*)(E  + idx) = make_float4(ew[1].v[1], ew[1].v[2], ew[1].v[3], ew[1].v[4]);
        *(float4*)(Hx + idx) = make_float4(hx[0], hx[1], hx[2], hx[3]);
        *(float4*)(Hy + idx) = make_float4(hy[0], hy[1], hy[2], hy[3]);

        // roll windows; load next row's data from LDS (s<3)
        ew[0] = ew[1]; ew[1] = ew[2]; ew[2] = ew[3];
        w3[0] = w3[1]; w3[1] = w3[2]; w3[2] = w3[3];
        w1r[0] = w1r[1]; w1r[1] = w1r[2];
        #pragma unroll
        for (int q = 0; q < 4; ++q) { x2c0[q] = x2c1[q]; x2c1[q] = w2r.v[3 + q]; }
        if (s < 3) {
            w3[3]  = l7 (&L3[b3 + 4 + s][0], lc);   // X3 row i+4  (max local 13)
            w2r    = l10(&L2[b2 + 3 + s][0], lc);   // X2 row i+3  (max local 10)
            w1r[2] = l7 (&L1[b2 + 3 + s][0], lc);   // X1 row i+3  (max local 10)
        }
    }
}

// ---------------------------------------------------------------------------
// Edge kernel: boundary row bands [0,7] and [4088,4095], fully guarded.
// ---------------------------------------------------------------------------
#define TRE 8
#define EROWSE 12
#define ECOLSE 136

__global__ __launch_bounds__(256) void edge_kernel(
    const float* __restrict__ X1, const float* __restrict__ X2,
    const float* __restrict__ X3, const float* __restrict__ w1,
    float* __restrict__ E, float* __restrict__ Hx, float* __restrict__ Hy)
{
    __shared__ float elds[EROWSE][ECOLSE];
    const int t    = threadIdx.x;
    const int row0 = blockIdx.y ? (NXg - TRE) : 0;
    const int col0 = blockIdx.x * 128;

    const float wv = w1[0];
    const float f0 = (wv - 1.0f) / 3.0f;
    const float f1 = -wv;
    const float f2 = wv;
    const float f3 = (1.0f - wv) / 3.0f;

    for (int cidx = t; cidx < EROWSE * ECOLSE; cidx += 256) {
        const int r  = cidx / ECOLSE;
        const int cc = cidx - r * ECOLSE;
        const int gr = row0 - 2 + r;
        const int gc = col0 - 4 + cc;
        float e = 0.0f;
        if (gr >= 0 && gr < NXg && gc >= 0 && gc < NYg) {
            const size_t idx = (size_t)gr * NYg + gc;
            const float x1 = X1[idx];
            if (gr == 0 || gr == NXg - 1 || gc == 0 || gc == NYg - 1) {
                e = x1;
            } else {
                float e1 = x1 + C * (X3[idx] - X3[idx - NYg])
                              - C * (X2[idx] - X2[idx - 1]);
                if (gr >= 2 && gr <= NXg - 3 && gc >= 2 && gc <= NYg - 3) {
                    e1 += C * (f0 * X3[idx - 2 * NYg] + f1 * X3[idx - NYg]
                             + f2 * X3[idx] + f3 * X3[idx + NYg])
                        - C * (f0 * X2[idx - 2] + f1 * X2[idx - 1]
                             + f2 * X2[idx] + f3 * X2[idx + 1]);
                }
                e = e1;
            }
        }
        elds[r][cc] = e;
    }
    __syncthreads();

    for (int cidx = t; cidx < TRE * 128; cidx += 256) {
        const int hr  = cidx >> 7;
        const int tc  = cidx & 127;
        const int gr  = row0 + hr;
        const int gcc = col0 + tc;
        const size_t idx = (size_t)gr * NYg + gcc;
        const int lr  = hr + 2;
        const int lc2 = tc + 4;

        const float ec = elds[lr][lc2];
        E[idx] = ec;

        const float x1 = X1[idx];

        float hx = X2[idx];
        if (gr >= 1 && gr <= NXg - 2 && gcc <= NYg - 2)
            hx -= C * (X1[idx + 1] - x1);
        if (gr >= 2 && gr <= NXg - 3 && gcc >= 1 && gcc <= NYg - 3) {
            hx -= C * (f0 * elds[lr][lc2 - 1] + f1 * ec
                     + f2 * elds[lr][lc2 + 1] + f3 * elds[lr][lc2 + 2]);
        }
        Hx[idx] = hx;

        float hy = X3[idx];
        if (gr <= NXg - 2 && gcc >= 1 && gcc <= NYg - 2)
            hy += C * (X1[idx + NYg] - x1);
        if (gr >= 1 && gr <= NXg - 3 && gcc >= 2 && gcc <= NYg - 3) {
            hy += C * (f0 * elds[lr - 1][lc2] + f1 * ec
                     + f2 * elds[lr + 1][lc2] + f3 * elds[lr + 2][lc2]);
        }
        Hy[idx] = hy;
    }
}

extern "C" void kernel_launch(void* const* d_in, const int* in_sizes, int n_in,
                              void* d_out, int out_size, void* d_ws, size_t ws_size,
                              hipStream_t stream) {
    const float* X1 = (const float*)d_in[0];
    const float* X2 = (const float*)d_in[1];
    const float* X3 = (const float*)d_in[2];
    const float* w1 = (const float*)d_in[3];

    float* E  = (float*)d_out;
    float* Hx = (float*)d_out + (size_t)NXg * NYg;
    float* Hy = (float*)d_out + 2 * (size_t)NXg * NYg;

    edge_kernel<<<dim3(32, 2), 256, 0, stream>>>(X1, X2, X3, w1, E, Hx, Hy);
    band_kernel<<<dim3(NPANEL, NBANDS), 128, 0, stream>>>(X1, X2, X3, w1, E, Hx, Hy);
}